// Round 9
// baseline (1572.205 us; speedup 1.0000x reference)
//
#include <hip/hip_runtime.h>
#include <hip/hip_bf16.h>

typedef __hip_bfloat16 bf16;
typedef unsigned int u32;
typedef unsigned long long u64;

constexpr int N   = 50000;
constexpr int E   = 1600000;
constexpr int C   = 128;             // channels (H * 32)
constexpr int H   = 4;               // heads
constexpr int NB  = 784;             // dst buckets of 64 nodes (784*64 = 50176)
constexpr int CAP = 2560;            // pair-region capacity per bucket (mean 2041, +11 sigma)
constexpr int CHUNK = 4096;          // edges per kbin block
constexpr float NEG  = 0.2f;
constexpr float SEPS = 1e-16f;
constexpr float LEPS = 1e-5f;

__device__ __forceinline__ float lo16(u32 v) { return __uint_as_float(v << 16); }
__device__ __forceinline__ float hi16(u32 v) { return __uint_as_float(v & 0xFFFF0000u); }

// K1: h = x @ W, 16 nodes per block. x tile in LDS; W read from global (L1-hot).
// h stored bf16. Fused attention dots a_s, a_d.
__global__ __launch_bounds__(256) void k1_gemm(
    const float* __restrict__ x, const float* __restrict__ W,
    const float* __restrict__ att_s, const float* __restrict__ att_d,
    bf16* __restrict__ hb, float* __restrict__ as_, float* __restrict__ ad_)
{
    const int nb = blockIdx.x * 16;
    const int t  = threadIdx.x;
    __shared__ float sx[16 * 128];
    const float4* xg = (const float4*)(x + nb * 128);
    ((float4*)sx)[t]       = xg[t];
    ((float4*)sx)[t + 256] = xg[t + 256];
    __syncthreads();

    const int c = t & 127;           // output channel
    const int g = t >> 7;            // node group (0/1) of 8 nodes
    const float* xb = sx + (g << 10);
    float acc[8] = {0.f, 0.f, 0.f, 0.f, 0.f, 0.f, 0.f, 0.f};

    for (int k = 0; k < 128; k += 4) {
        const float w0 = W[(k + 0) * 128 + c];
        const float w1 = W[(k + 1) * 128 + c];
        const float w2 = W[(k + 2) * 128 + c];
        const float w3 = W[(k + 3) * 128 + c];
#pragma unroll
        for (int j = 0; j < 8; ++j) {
            const float4 xv = *(const float4*)(xb + j * 128 + k);
            acc[j] = fmaf(xv.x, w0, fmaf(xv.y, w1, fmaf(xv.z, w2, fmaf(xv.w, w3, acc[j]))));
        }
    }

    const int lane = t & 63;
    const int head = c >> 5;
    const float asc = att_s[c], adc = att_d[c];
#pragma unroll
    for (int j = 0; j < 8; ++j) {
        const int node = nb + (g << 3) + j;
        hb[node * 128 + c] = __float2bfloat16(acc[j]);
        float vs = acc[j] * asc;
        float vd = acc[j] * adc;
#pragma unroll
        for (int off = 16; off; off >>= 1) {
            vs += __shfl_xor(vs, off, 64);
            vd += __shfl_xor(vd, off, 64);
        }
        if ((lane & 31) == 0) {
            as_[node * H + head] = vs;
            ad_[node * H + head] = vd;
        }
    }
}

// KBIN: bin edges into NB dst-buckets as (src,dst) u64 pairs.
// Two-phase per 4096-edge chunk: LDS count -> global reserve -> re-read & scatter.
// Per-bucket runs are written temporally close -> L2 merges lines (low write amp).
__global__ __launch_bounds__(256) void kbin(
    const int* __restrict__ ei, u32* __restrict__ gcur, u64* __restrict__ pairs)
{
    __shared__ u32 lcnt[NB], lbase[NB], lfill[NB];
    const int t = threadIdx.x;
    const int base = blockIdx.x * CHUNK;
    const int nE = min(CHUNK, E - base);
    for (int i = t; i < NB; i += 256) lcnt[i] = 0;
    __syncthreads();
    for (int i = t; i < nE; i += 256)
        atomicAdd(&lcnt[((u32)ei[E + base + i]) >> 6], 1u);
    __syncthreads();
    for (int i = t; i < NB; i += 256) {
        u32 cb = lcnt[i];
        lbase[i] = cb ? atomicAdd(&gcur[i], cb) : 0u;
        lfill[i] = 0u;
    }
    __syncthreads();
    for (int i = t; i < nE; i += 256) {
        u32 src = (u32)ei[base + i];
        u32 dst = (u32)ei[E + base + i];
        u32 b = dst >> 6;
        u32 pos = atomicAdd(&lfill[b], 1u);
        pairs[(size_t)b * CAP + lbase[b] + pos] = (u64)src | ((u64)dst << 32);
    }
}

// KAGG: one block per 64-node bucket. f32 accumulator lives in LDS
// (split even/odd channel planes -> conflict-free ds ops). Self-loop init,
// wave-per-edge (2-wide) accumulate, fused bias+LayerNorm+ELU epilogue.
__global__ __launch_bounds__(256) void kagg(
    const u64* __restrict__ pairs, const u32* __restrict__ gcur,
    const u32* __restrict__ hb, const float* __restrict__ as_,
    const float* __restrict__ ad_,
    const float* __restrict__ bias, const float* __restrict__ gamma,
    const float* __restrict__ beta, float* __restrict__ out)
{
    __shared__ float accE[64][64];   // channel 2k   -> accE[j][k]
    __shared__ float accO[64][64];   // channel 2k+1 -> accO[j][k]
    __shared__ float den[64][4];
    __shared__ float adn[64][4];
    const int b = blockIdx.x;
    const int t = threadIdx.x;
    const int wave = t >> 6, lane = t & 63;
    const int head = lane >> 4;
    const int n0 = b * 64;

    {   // stage ad for bucket nodes (64*4 entries, one per thread)
        int j = t >> 2, hh = t & 3;
        int n = n0 + j;
        adn[j][hh] = (n < N) ? ad_[n * H + hh] : 0.f;
    }
    __syncthreads();

    // self-loop init: wave w owns nodes j in [w*16, w*16+16)
    for (int j = wave * 16; j < wave * 16 + 16; ++j) {
        int n = n0 + j;
        if (n >= N) continue;
        float l = as_[n * H + head] + adn[j][head];
        l = fmaxf(l, NEG * l);
        float w = __expf(l);
        u32 hv = hb[(size_t)n * 64 + lane];
        accE[j][lane] = w * lo16(hv);
        accO[j][lane] = w * hi16(hv);
        if ((lane & 15) == 0) den[j][head] = w;
    }
    __syncthreads();

    // edge accumulation, 2 edges in flight per wave
    const int cntb = (int)gcur[b];
    const u64* pr = pairs + (size_t)b * CAP;
    for (int e0 = wave * 2; e0 < cntb; e0 += 8) {
        const u64 p0 = pr[e0];
        const bool has1 = (e0 + 1 < cntb);
        const u64 p1 = has1 ? pr[e0 + 1] : p0;
        const u32 s0 = (u32)p0, j0 = ((u32)(p0 >> 32)) & 63u;
        const u32 s1 = (u32)p1, j1 = ((u32)(p1 >> 32)) & 63u;
        const float a0 = as_[s0 * H + head];
        const float a1 = as_[s1 * H + head];
        const u32 h0 = hb[(size_t)s0 * 64 + lane];
        const u32 h1 = hb[(size_t)s1 * 64 + lane];
        float l0 = a0 + adn[j0][head]; l0 = fmaxf(l0, NEG * l0);
        float l1 = a1 + adn[j1][head]; l1 = fmaxf(l1, NEG * l1);
        const float w0 = __expf(l0);
        const float w1 = has1 ? __expf(l1) : 0.f;
        if ((lane & 15) == 0) atomicAdd(&den[j0][head], w0);
        atomicAdd(&accE[j0][lane], w0 * lo16(h0));
        atomicAdd(&accO[j0][lane], w0 * hi16(h0));
        if (has1) {
            if ((lane & 15) == 0) atomicAdd(&den[j1][head], w1);
            atomicAdd(&accE[j1][lane], w1 * lo16(h1));
            atomicAdd(&accO[j1][lane], w1 * hi16(h1));
        }
    }
    __syncthreads();

    // epilogue: softmax divide + bias + LayerNorm + ELU -> f32 out
    const float2 bias2 = ((const float2*)bias)[lane];
    const float2 gam2  = ((const float2*)gamma)[lane];
    const float2 bet2  = ((const float2*)beta)[lane];
    for (int j = wave * 16; j < wave * 16 + 16; ++j) {
        int n = n0 + j;
        if (n >= N) continue;
        const float inv_den = 1.f / (den[j][head] + SEPS);
        float v0 = accE[j][lane] * inv_den + bias2.x;
        float v1 = accO[j][lane] * inv_den + bias2.y;
        float sum = v0 + v1;
#pragma unroll
        for (int off = 32; off; off >>= 1) sum += __shfl_xor(sum, off, 64);
        const float mu = sum * (1.0f / C);
        const float d0 = v0 - mu, d1 = v1 - mu;
        float sq = d0 * d0 + d1 * d1;
#pragma unroll
        for (int off = 32; off; off >>= 1) sq += __shfl_xor(sq, off, 64);
        const float inv = rsqrtf(sq * (1.0f / C) + LEPS);
        float y0 = d0 * inv * gam2.x + bet2.x;
        float y1 = d1 * inv * gam2.y + bet2.y;
        y0 = y0 > 0.f ? y0 : __expf(y0) - 1.f;
        y1 = y1 > 0.f ? y1 : __expf(y1) - 1.f;
        float2 o; o.x = y0; o.y = y1;
        *(float2*)(out + (size_t)n * C + lane * 2) = o;
    }
}

extern "C" void kernel_launch(void* const* d_in, const int* in_sizes, int n_in,
                              void* d_out, int out_size, void* d_ws, size_t ws_size,
                              hipStream_t stream)
{
    const float* x     = (const float*)d_in[0];
    const int*   ei    = (const int*)  d_in[1];
    const float* W     = (const float*)d_in[2];
    const float* att_s = (const float*)d_in[3];
    const float* att_d = (const float*)d_in[4];
    const float* bias  = (const float*)d_in[5];
    const float* gamma = (const float*)d_in[6];
    const float* beta  = (const float*)d_in[7];
    float* out = (float*)d_out;

    // ws (~30.5 MB): hb bf16[N*C] | as_ f32[N*H] | ad_ f32[N*H]
    //              | pairs u64[NB*CAP] | gcur u32[NB]
    char* p = (char*)d_ws;
    bf16*  hb    = (bf16*)p;   p += (size_t)N * C * sizeof(bf16);
    float* as_   = (float*)p;  p += (size_t)N * H * sizeof(float);
    float* ad_   = (float*)p;  p += (size_t)N * H * sizeof(float);
    u64*   pairs = (u64*)p;    p += (size_t)NB * CAP * sizeof(u64);
    u32*   gcur  = (u32*)p;

    hipMemsetAsync(gcur, 0, NB * sizeof(u32), stream);
    k1_gemm<<<N / 16, 256, 0, stream>>>(x, W, att_s, att_d, hb, as_, ad_);
    kbin<<<(E + CHUNK - 1) / CHUNK, 256, 0, stream>>>(ei, gcur, pairs);
    kagg<<<NB, 256, 0, stream>>>(pairs, gcur, (const u32*)hb, as_, ad_,
                                 bias, gamma, beta, out);
}

// Round 10
// 245.374 us; speedup vs baseline: 6.4074x; 6.4074x over previous
//
#include <hip/hip_runtime.h>
#include <hip/hip_bf16.h>

typedef __hip_bfloat16 bf16;
typedef unsigned int u32;
typedef unsigned short u16;

constexpr int N   = 50000;
constexpr int E   = 1600000;
constexpr int C   = 128;             // channels (H * 32)
constexpr int H   = 4;               // heads
constexpr int NB  = 782;             // dst buckets of 64 nodes (782*64 >= 50000)
constexpr int CAP = 2560;            // pairs capacity per bucket (mean 2048, +11 sigma)
constexpr int CHUNK = 4096;          // edges per kbin block
constexpr float NEG  = 0.2f;
constexpr float SEPS = 1e-16f;
constexpr float LEPS = 1e-5f;

__device__ __forceinline__ float lo16(u32 v) { return __uint_as_float(v << 16); }
__device__ __forceinline__ float hi16(u32 v) { return __uint_as_float(v & 0xFFFF0000u); }

// K1: h = x @ W, 16 nodes per block. x tile in LDS; W from global (L1/L2-hot).
// h stored bf16. Fused attention dots a_s, a_d.
__global__ __launch_bounds__(256) void k1_gemm(
    const float* __restrict__ x, const float* __restrict__ W,
    const float* __restrict__ att_s, const float* __restrict__ att_d,
    bf16* __restrict__ hb, float* __restrict__ as_, float* __restrict__ ad_)
{
    const int nb = blockIdx.x * 16;
    const int t  = threadIdx.x;
    __shared__ float sx[16 * 128];
    const float4* xg = (const float4*)(x + nb * 128);
    ((float4*)sx)[t]       = xg[t];
    ((float4*)sx)[t + 256] = xg[t + 256];
    __syncthreads();

    const int c = t & 127;           // output channel
    const int g = t >> 7;            // node group (0/1) of 8 nodes
    const float* xb = sx + (g << 10);
    float acc[8] = {0.f, 0.f, 0.f, 0.f, 0.f, 0.f, 0.f, 0.f};

    for (int k = 0; k < 128; k += 4) {
        const float w0 = W[(k + 0) * 128 + c];
        const float w1 = W[(k + 1) * 128 + c];
        const float w2 = W[(k + 2) * 128 + c];
        const float w3 = W[(k + 3) * 128 + c];
#pragma unroll
        for (int j = 0; j < 8; ++j) {
            const float4 xv = *(const float4*)(xb + j * 128 + k);
            acc[j] = fmaf(xv.x, w0, fmaf(xv.y, w1, fmaf(xv.z, w2, fmaf(xv.w, w3, acc[j]))));
        }
    }

    const int lane = t & 63;
    const int head = c >> 5;
    const float asc = att_s[c], adc = att_d[c];
#pragma unroll
    for (int j = 0; j < 8; ++j) {
        const int node = nb + (g << 3) + j;
        hb[node * 128 + c] = __float2bfloat16(acc[j]);
        float vs = acc[j] * asc;
        float vd = acc[j] * adc;
#pragma unroll
        for (int off = 16; off; off >>= 1) {
            vs += __shfl_xor(vs, off, 64);
            vd += __shfl_xor(vd, off, 64);
        }
        if ((lane & 31) == 0) {
            as_[node * H + head] = vs;
            ad_[node * H + head] = vd;
        }
    }
}

// KBIN: bin edges into NB dst-buckets as packed u32 (src | (dst&63)<<16).
// Two-phase per chunk: LDS int count -> global reserve -> scatter.
// Bucket runs are temporally clustered -> L2 merges write lines.
__global__ __launch_bounds__(256) void kbin(
    const int* __restrict__ ei, u32* __restrict__ gcur, u32* __restrict__ pairs)
{
    __shared__ u32 lcnt[NB], lbase[NB], lfill[NB];
    const int t = threadIdx.x;
    const int base = blockIdx.x * CHUNK;
    const int nE = min(CHUNK, E - base);
    for (int i = t; i < NB; i += 256) lcnt[i] = 0;
    __syncthreads();
    for (int i = t; i < nE; i += 256)
        atomicAdd(&lcnt[((u32)ei[E + base + i]) >> 6], 1u);
    __syncthreads();
    for (int i = t; i < NB; i += 256) {
        u32 cb = lcnt[i];
        lbase[i] = cb ? atomicAdd(&gcur[i], cb) : 0u;
        lfill[i] = 0u;
    }
    __syncthreads();
    for (int i = t; i < nE; i += 256) {
        u32 src = (u32)ei[base + i];
        u32 dst = (u32)ei[E + base + i];
        u32 b = dst >> 6;
        u32 pos = atomicAdd(&lfill[b], 1u);
        pairs[(size_t)b * CAP + lbase[b] + pos] = src | ((dst & 63u) << 16);
    }
}

// KSCAN: one wave — exclusive scan of gcur[NB] -> bbase; row_ptr[N] = E.
__global__ __launch_bounds__(64) void kscan(
    const u32* __restrict__ gcur, u32* __restrict__ bbase, int* __restrict__ row_ptr)
{
    const int t = threadIdx.x;
    u32 vals[13];
    u32 s = 0;
#pragma unroll
    for (int i = 0; i < 13; ++i) {
        int idx = t * 13 + i;
        u32 v = (idx < NB) ? gcur[idx] : 0u;
        vals[i] = s; s += v;
    }
    u32 incl = s;
#pragma unroll
    for (int off = 1; off < 64; off <<= 1) {
        u32 u = __shfl_up(incl, off, 64);
        if (t >= off) incl += u;
    }
    const u32 excl = incl - s;
#pragma unroll
    for (int i = 0; i < 13; ++i) {
        int idx = t * 13 + i;
        if (idx < NB) bbase[idx] = excl + vals[i];
    }
    if (t == 0) row_ptr[N] = E;
}

// KFILL2: block per bucket. Count per node (int LDS atomics), wave scan,
// write row_ptr and scatter u16 col within the bucket's narrow region.
__global__ __launch_bounds__(256) void kfill2(
    const u32* __restrict__ pairs, const u32* __restrict__ gcur,
    const u32* __restrict__ bbase, int* __restrict__ row_ptr, u16* __restrict__ col)
{
    __shared__ int jcnt[64], joff[64], jcur[64];
    const int b = blockIdx.x, t = threadIdx.x;
    const int cntb = (int)gcur[b];
    const int base = (int)bbase[b];
    if (t < 64) jcnt[t] = 0;
    __syncthreads();
    const u32* pr = pairs + (size_t)b * CAP;
    for (int i = t; i < cntb; i += 256) atomicAdd(&jcnt[pr[i] >> 16], 1);
    __syncthreads();
    if (t < 64) {
        int v = jcnt[t], incl = v;
#pragma unroll
        for (int off = 1; off < 64; off <<= 1) {
            int u = __shfl_up(incl, off, 64);
            if (t >= off) incl += u;
        }
        joff[t] = incl - v;
        const int n = b * 64 + t;
        if (n < N) row_ptr[n] = base + joff[t];
        jcur[t] = 0;
    }
    __syncthreads();
    for (int i = t; i < cntb; i += 256) {
        const u32 p = pr[i];
        const int j = p >> 16;
        const int pos = atomicAdd(&jcur[j], 1);
        col[base + joff[j] + pos] = (u16)(p & 0xFFFFu);
    }
}

// KD: fused attention-softmax aggregation + bias + LayerNorm + ELU -> f32 out.
// One wave per node, register accumulation (no atomics), bf16 h, u16 col.
__global__ __launch_bounds__(256) void kd_agg_ln(
    const int* __restrict__ row_ptr, const u16* __restrict__ col,
    const u32* __restrict__ hb, const float* __restrict__ as_,
    const float* __restrict__ ad_,
    const float* __restrict__ bias, const float* __restrict__ gamma,
    const float* __restrict__ beta, float* __restrict__ out)
{
    int gid = blockIdx.x * blockDim.x + threadIdx.x;
    int n = gid >> 6;
    if (n >= N) return;
    const int lane = gid & 63;
    const int head = lane >> 4;

    const float adn = ad_[n * H + head];
    // self-loop term (src == dst == n)
    float l = as_[n * H + head] + adn;
    l = fmaxf(l, NEG * l);
    float w = __expf(l);
    float den = w;
    u32 hv = hb[n * 64 + lane];
    float num0 = w * lo16(hv);
    float num1 = w * hi16(hv);

    int k = row_ptr[n];
    const int end = row_ptr[n + 1];
    for (; k + 4 <= end; k += 4) {
        const int s0 = col[k], s1 = col[k + 1], s2 = col[k + 2], s3 = col[k + 3];
        float l0 = as_[s0 * H + head] + adn;
        float l1 = as_[s1 * H + head] + adn;
        float l2 = as_[s2 * H + head] + adn;
        float l3 = as_[s3 * H + head] + adn;
        const u32 v0 = hb[s0 * 64 + lane];
        const u32 v1 = hb[s1 * 64 + lane];
        const u32 v2 = hb[s2 * 64 + lane];
        const u32 v3 = hb[s3 * 64 + lane];
        l0 = fmaxf(l0, NEG * l0); l1 = fmaxf(l1, NEG * l1);
        l2 = fmaxf(l2, NEG * l2); l3 = fmaxf(l3, NEG * l3);
        const float w0 = __expf(l0), w1 = __expf(l1);
        const float w2 = __expf(l2), w3 = __expf(l3);
        den += (w0 + w1) + (w2 + w3);
        num0 = fmaf(w0, lo16(v0), num0); num1 = fmaf(w0, hi16(v0), num1);
        num0 = fmaf(w1, lo16(v1), num0); num1 = fmaf(w1, hi16(v1), num1);
        num0 = fmaf(w2, lo16(v2), num0); num1 = fmaf(w2, hi16(v2), num1);
        num0 = fmaf(w3, lo16(v3), num0); num1 = fmaf(w3, hi16(v3), num1);
    }
    for (; k < end; ++k) {
        const int s = col[k];
        float ls = as_[s * H + head] + adn;
        ls = fmaxf(ls, NEG * ls);
        const float ws = __expf(ls);
        const u32 vs = hb[s * 64 + lane];
        den += ws;
        num0 = fmaf(ws, lo16(vs), num0);
        num1 = fmaf(ws, hi16(vs), num1);
    }

    const int c0 = lane * 2;
    const float inv_den = 1.f / (den + SEPS);
    float v0 = num0 * inv_den + bias[c0];
    float v1 = num1 * inv_den + bias[c0 + 1];

    float sum = v0 + v1;
#pragma unroll
    for (int off = 32; off; off >>= 1) sum += __shfl_xor(sum, off, 64);
    const float mu = sum * (1.0f / C);
    const float d0 = v0 - mu, d1 = v1 - mu;
    float sq = d0 * d0 + d1 * d1;
#pragma unroll
    for (int off = 32; off; off >>= 1) sq += __shfl_xor(sq, off, 64);
    const float inv = rsqrtf(sq * (1.0f / C) + LEPS);
    float y0 = d0 * inv * gamma[c0]     + beta[c0];
    float y1 = d1 * inv * gamma[c0 + 1] + beta[c0 + 1];
    y0 = y0 > 0.f ? y0 : __expf(y0) - 1.f;
    y1 = y1 > 0.f ? y1 : __expf(y1) - 1.f;
    float2 o; o.x = y0; o.y = y1;
    *(float2*)(out + (size_t)n * C + c0) = o;
}

extern "C" void kernel_launch(void* const* d_in, const int* in_sizes, int n_in,
                              void* d_out, int out_size, void* d_ws, size_t ws_size,
                              hipStream_t stream)
{
    const float* x     = (const float*)d_in[0];
    const int*   ei    = (const int*)  d_in[1];
    const float* W     = (const float*)d_in[2];
    const float* att_s = (const float*)d_in[3];
    const float* att_d = (const float*)d_in[4];
    const float* bias  = (const float*)d_in[5];
    const float* gamma = (const float*)d_in[6];
    const float* beta  = (const float*)d_in[7];
    float* out = (float*)d_out;

    // ws (~26 MB): hb bf16[N*C] | as_ | ad_ | pairs u32[NB*CAP] | col u16[E]
    //            | row_ptr int[N+1] | gcur u32[NB] | bbase u32[NB]
    char* p = (char*)d_ws;
    bf16*  hb      = (bf16*)p;   p += (size_t)N * C * sizeof(bf16);
    float* as_     = (float*)p;  p += (size_t)N * H * sizeof(float);
    float* ad_     = (float*)p;  p += (size_t)N * H * sizeof(float);
    u32*   pairs   = (u32*)p;    p += (size_t)NB * CAP * sizeof(u32);
    u16*   col     = (u16*)p;    p += ((size_t)E * sizeof(u16) + 15) & ~(size_t)15;
    int*   row_ptr = (int*)p;    p += ((size_t)(N + 1) * sizeof(int) + 15) & ~(size_t)15;
    u32*   gcur    = (u32*)p;    p += (size_t)NB * sizeof(u32);
    u32*   bbase   = (u32*)p;

    hipMemsetAsync(gcur, 0, NB * sizeof(u32), stream);
    k1_gemm<<<N / 16, 256, 0, stream>>>(x, W, att_s, att_d, hb, as_, ad_);
    kbin<<<(E + CHUNK - 1) / CHUNK, 256, 0, stream>>>(ei, gcur, pairs);
    kscan<<<1, 64, 0, stream>>>(gcur, bbase, row_ptr);
    kfill2<<<NB, 256, 0, stream>>>(pairs, gcur, bbase, row_ptr, col);
    kd_agg_ln<<<(N * 64) / 256, 256, 0, stream>>>(
        row_ptr, col, (const u32*)hb, as_, ad_, bias, gamma, beta, out);
}